// Round 3
// baseline (218.505 us; speedup 1.0000x reference)
//
#include <hip/hip_runtime.h>

// VQ-VAE vector quantizer, MI355X (gfx950).
//   inputs : z (8,256,16,16,16) fp32, codebook (1024,256) fp32
//   output : quant (8,256,16,16,16) ++ idx (8,16,16,16) ++ loss (1), fp32 flat
//
// Round 9: wave-independent Phase C + k-split occupancy doubling.
//   * Phase C barrier-free: B-fragments read straight from the L2-resident
//     pre-swizzled bf16 codebook (coalesced 16B/lane), no LDS staging, no
//     lockstep -- waves hide each other's latency, compiler prefetches deep.
//   * k-split: 4 waves/block = {token group 0/1} x {codebook half 0/1} over
//     TOK_BLK=32 tokens; grid 1024 -> 4 blocks/CU -> 16 waves/CU (2x).
//     Candidate lists merged via LDS atomicAdd; Phase D lex-min (D,k) is
//     order-independent -> bit-deterministic result unchanged.
//   * Sz spread over all 256 lanes (exact np __fadd_rn tree via width-8
//     shfl_xor; commutative pairs bit-identical).
//   * Phase D/E float4 e-row gathers, fused loss (verified round 8).

#define K_CODES 1024
#define DIM 256
#define N_TOK 32768
#define SPATIAL 4096
#define TOK_BLK 32
#define NBLK (N_TOK / TOK_BLK)
#define CAP 28
#define MARGIN 1e-3f

typedef __attribute__((ext_vector_type(8))) short short8;
typedef __attribute__((ext_vector_type(4))) float float4v;

// ws layout in floats
#define WS_LOSS 0
#define WS_CNT 8      // unsigned completion counter (byte 32)
#define WS_E2 16      // 1024 floats: Se[k] (np pairwise)
#define WS_EB 2048    // 262144 bf16: codebook, B-fragment order

#define O_IDX (8 * DIM * SPATIAL)  // 8388608
#define O_LOSS (O_IDX + N_TOK)     // 8421376

__device__ __forceinline__ short f2bf(float v) {  // RTNE fp32->bf16 bits
  unsigned u = __float_as_uint(v);
  u = (u + 0x7fffu + ((u >> 16) & 1u)) >> 16;
  return (short)u;
}

// prep: Se[k] np-pairwise (exact order, parallelized); codebook -> bf16 in
// MFMA B-fragment order, 16B chunk stores.  (verified round 7/8)
__global__ __launch_bounds__(256) void prep_kernel(const float* __restrict__ e,
                                                   float* __restrict__ ws) {
  __shared__ float sq[DIM];
  __shared__ __align__(16) short sbf[DIM];
  __shared__ float chv[16];
  int k = blockIdx.x, d = threadIdx.x;
  float v = e[k * DIM + d];
  sbf[d] = f2bf(v);
  sq[d] = __fmul_rn(v, v);
  __syncthreads();
  if (d < 32) {  // 16B chunk stores of the fragment layout
    int f = d >> 2, q = d & 3;
    int stage = k >> 6, ct = (k >> 4) & 3, nn = k & 15;
    short8 chunk = *(const short8*)(sbf + f * 32 + q * 8);
    int off8 = ((stage * 4 + ct) * 8 + f) * 64 + q * 16 + nn;
    ((short8*)(ws + WS_EB))[off8] = chunk;
  }
  if (d < 16) {  // chain (blk=d>>3, j=d&7): exact np serial order i=0..15
    int blkb = d >> 3, j = d & 7;
    const float* x = sq + blkb * 128;
    float c = x[j];
#pragma unroll
    for (int i = 1; i < 16; i++) c = __fadd_rn(c, x[i * 8 + j]);
    chv[d] = c;
  }
  __syncthreads();
  if (d == 0) {  // exact np_pairwise128 combine tree, then blk0+blk1
    float a0 = __fadd_rn(__fadd_rn(chv[0], chv[1]), __fadd_rn(chv[2], chv[3]));
    float a1 = __fadd_rn(__fadd_rn(chv[4], chv[5]), __fadd_rn(chv[6], chv[7]));
    float resA = __fadd_rn(a0, a1);
    float b0 = __fadd_rn(__fadd_rn(chv[8], chv[9]), __fadd_rn(chv[10], chv[11]));
    float b1 = __fadd_rn(__fadd_rn(chv[12], chv[13]), __fadd_rn(chv[14], chv[15]));
    float resB = __fadd_rn(b0, b1);
    ws[WS_E2 + k] = __fadd_rn(resA, resB);
    if (k == 0) {
      ws[WS_LOSS] = 0.f;
      ((unsigned*)ws)[WS_CNT] = 0u;
    }
  }
}

__global__ __launch_bounds__(256, 4) void main_kernel(const float* __restrict__ z,
                                                      const float* __restrict__ e,
                                                      float* __restrict__ ws,
                                                      float* __restrict__ out) {
  __shared__ unsigned short cand[TOK_BLK][CAP];
  __shared__ float cands[TOK_BLK][CAP];
  __shared__ float aminv[2][TOK_BLK];  // per-k-half final approx min
  __shared__ int cnt[TOK_BLK];
  __shared__ float Szs[TOK_BLK];
  __shared__ int mini_sh[TOK_BLK];
  __shared__ float red[4];

  int tid = threadIdx.x, w = tid >> 6, lane = tid & 63;
  int quad = lane >> 4, nn = lane & 15;
  int g = w & 1, kh = w >> 1;  // token group, codebook half
  int n0 = blockIdx.x * TOK_BLK;
  int b = n0 >> 12, s0 = n0 & 4095;
  const float* zb = z + (size_t)b * DIM * SPATIAL + s0;
  const float* Se = ws + WS_E2;
  const short8* eBf = (const short8*)(ws + WS_EB);
  if (tid < TOK_BLK) cnt[tid] = 0;
  __syncthreads();  // cnt visible before any wave's appends

  // ---- Sz (exact np pairwise), 256 lanes: lane = (token tt, pair m);
  //      chains 2m,2m+1 share blk, adjacent j. shfl_xor tree reproduces the
  //      exact __fadd_rn pairing (commutative pairs are bit-identical). ----
  {
    int tt = tid >> 3, m = tid & 7;
    int blkb = m >> 2, j0 = (2 * m) & 7;
    const float* zp = zb + tt;
    float v0 = zp[(size_t)(blkb * 128 + j0) * SPATIAL];
    float v1 = zp[(size_t)(blkb * 128 + j0 + 1) * SPATIAL];
    float r0 = __fmul_rn(v0, v0), r1 = __fmul_rn(v1, v1);
    for (int i = 1; i < 16; i++) {
      v0 = zp[(size_t)(blkb * 128 + i * 8 + j0) * SPATIAL];
      v1 = zp[(size_t)(blkb * 128 + i * 8 + j0 + 1) * SPATIAL];
      r0 = __fadd_rn(r0, __fmul_rn(v0, v0));
      r1 = __fadd_rn(r1, __fmul_rn(v1, v1));
    }
    float p = __fadd_rn(r0, r1);                    // (r2m + r2m+1)
    float q1 = __fadd_rn(p, __shfl_xor(p, 1, 8));   // (p0+p1) | (p2+p3) ...
    float q2 = __fadd_rn(q1, __shfl_xor(q1, 2, 8)); // blk0res | blk1res
    float tot = __fadd_rn(q2, __shfl_xor(q2, 4, 8));// blk0res + blk1res
    if (m == 0) Szs[tt] = tot;
  }

  // ---- A fragments (z -> bf16) in registers: token = g*16+nn,
  //      frag f holds k-dim d = f*32 + quad*8 + j ----
  int tokA = g * 16 + nn;
  short8 A[8];
#pragma unroll
  for (int f = 0; f < 8; f++) {
    short8 a;
#pragma unroll
    for (int j = 0; j < 8; j++) {
      int d = f * 32 + quad * 8 + j;
      a[j] = f2bf(zb[(size_t)d * SPATIAL + tokA]);
    }
    A[f] = a;
  }

  // ---- Phase C: MFMA filter, barrier-free; wave scans its codebook half.
  //      B-frags coalesced from L2-resident swizzled codebook. ----
  float thr[4] = {3.4e38f, 3.4e38f, 3.4e38f, 3.4e38f};
  for (int s8 = 0; s8 < 8; s8++) {
    int stage = kh * 8 + s8;
    for (int ct = 0; ct < 4; ct++) {
      int kbase = stage * 64 + ct * 16;
      float4v C = {0.f, 0.f, 0.f, 0.f};
      const short8* Bp = eBf + (size_t)((stage * 4 + ct) * 8) * 64;
#pragma unroll
      for (int f = 0; f < 8; f++) {
        short8 Bf = Bp[f * 64 + lane];  // global_load_dwordx4, coalesced
        C = __builtin_amdgcn_mfma_f32_16x16x32_bf16(A[f], Bf, C, 0, 0, 0);
      }
      float SeK = Se[kbase + nn];  // col = code = nn
      float sv[4];
      bool pr[4];
#pragma unroll
      for (int r = 0; r < 4; r++) {  // row = token = quad*4 + r
        float s = fmaf(-2.f, C[r], SeK);
        float m = s;  // rowmin across the 16 lanes of this row
        m = fminf(m, __shfl_xor(m, 1, 16));
        m = fminf(m, __shfl_xor(m, 2, 16));
        m = fminf(m, __shfl_xor(m, 4, 16));
        m = fminf(m, __shfl_xor(m, 8, 16));
        thr[r] = fminf(thr[r], m);
        sv[r] = s;
        pr[r] = s < thr[r] + MARGIN;
      }
      if (__ballot(pr[0] | pr[1] | pr[2] | pr[3])) {  // rare path
#pragma unroll
        for (int r = 0; r < 4; r++) {
          unsigned long long bl = __ballot(pr[r]);
          unsigned grp = (unsigned)((bl >> (quad * 16)) & 0xffffULL);
          if (grp) {  // quad-uniform
            int tb = g * 16 + quad * 4 + r;
            int base = 0;
            if (nn == 0) base = atomicAdd(&cnt[tb], __popc(grp));
            base = __shfl(base, quad * 16);  // broadcast from quad's lane 0
            if (pr[r]) {
              int pos = base + __popc(grp & ((1u << nn) - 1u));
              if (pos < CAP) {
                cand[tb][pos] = (unsigned short)(kbase + nn);
                cands[tb][pos] = sv[r];
              }
            }
          }
        }
      }
    }
  }
  // publish per-(token, k-half) final approx min
#pragma unroll
  for (int r = 0; r < 4; r++)
    if (nn == 0) aminv[kh][g * 16 + quad * 4 + r] = thr[r];
  __syncthreads();  // candidates + aminv + Szs ready

  // ---- Phase D: exact recheck. Wave w owns tokens w*8..w*8+7; lane =
  //      (token tl, oct); candidate slots oct::8. Lex-min (D,k) over the
  //      candidate set is append-order-independent -> deterministic. ----
  int tl = lane >> 3, oct = lane & 7;
  int tb = w * 8 + tl;
  int cc = cnt[tb];
  int cl = cc < CAP ? cc : CAP;
  float bestD = 3.4e38f;
  int bestk = 0x7fffffff;
  {
    const float* zp = zb + tb;
    float amin = fminf(aminv[0][tb], aminv[1][tb]);
    float Szn = Szs[tb];
    for (int c = oct; c < cl; c += 8) {
      if (cands[tb][c] >= amin + MARGIN) continue;  // pruned
      int k = cand[tb][c];
      const float* er = e + (size_t)k * DIM;
      float acc = 0.f;
#pragma unroll 4
      for (int dd = 0; dd < DIM; dd += 4) {
        float4 e4 = *(const float4*)(er + dd);
        acc = fmaf(zp[(size_t)(dd + 0) * SPATIAL], e4.x, acc);
        acc = fmaf(zp[(size_t)(dd + 1) * SPATIAL], e4.y, acc);
        acc = fmaf(zp[(size_t)(dd + 2) * SPATIAL], e4.z, acc);
        acc = fmaf(zp[(size_t)(dd + 3) * SPATIAL], e4.w, acc);
      }
      float D = __fsub_rn(__fadd_rn(Szn, Se[k]), __fmul_rn(2.f, acc));
      if (D < bestD || (D == bestD && k < bestk)) { bestD = D; bestk = k; }
    }
  }
#pragma unroll
  for (int off = 4; off >= 1; off >>= 1) {  // merge the 8 lanes per token
    float oD = __shfl_down(bestD, off, 8);
    int ok = __shfl_down(bestk, off, 8);
    if (oD < bestD || (oD == bestD && ok < bestk)) { bestD = oD; bestk = ok; }
  }
  if (oct == 0 && cc <= CAP) {
    mini_sh[tb] = bestk;
    out[O_IDX + n0 + tb] = (float)bestk;
  }
  // overflow tokens: exact full scan by the whole wave (deterministic)
  for (int t = 0; t < 8; t++) {
    int tb2 = w * 8 + t;
    if (cnt[tb2] > CAP) {
      const float* zq = zb + tb2;
      float Szn = Szs[tb2];
      float bD = 3.4e38f;
      int bk = 0x7fffffff;
      for (int k = lane; k < K_CODES; k += 64) {
        const float* er = e + (size_t)k * DIM;
        float acc = 0.f;
#pragma unroll 4
        for (int dd = 0; dd < DIM; dd += 4) {
          float4 e4 = *(const float4*)(er + dd);
          acc = fmaf(zq[(size_t)(dd + 0) * SPATIAL], e4.x, acc);
          acc = fmaf(zq[(size_t)(dd + 1) * SPATIAL], e4.y, acc);
          acc = fmaf(zq[(size_t)(dd + 2) * SPATIAL], e4.z, acc);
          acc = fmaf(zq[(size_t)(dd + 3) * SPATIAL], e4.w, acc);
        }
        float D = __fsub_rn(__fadd_rn(Szn, Se[k]), __fmul_rn(2.f, acc));
        if (D < bD || (D == bD && k < bk)) { bD = D; bk = k; }
      }
#pragma unroll
      for (int m = 1; m < 64; m <<= 1) {
        float oD = __shfl_xor(bD, m);
        int ok = __shfl_xor(bk, m);
        if (oD < bD || (oD == bD && ok < bk)) { bD = oD; bk = ok; }
      }
      if (lane == 0) {
        mini_sh[tb2] = bk;
        out[O_IDX + n0 + tb2] = (float)bk;
      }
    }
  }
  __syncthreads();  // mini_sh ready for all waves

  // ---- Phase E: quant gather + store + loss. lane = (h, token t);
  //      wave w covers dims [w*64, w*64+64), h-halves of 32. ----
  int h = lane >> 5, t = lane & 31;
  int mten = mini_sh[t];
  const float* erow = e + (size_t)mten * DIM;
  float* op = out + (size_t)b * DIM * SPATIAL + s0;
  float sumsq = 0.f;
#pragma unroll 2
  for (int i4 = 0; i4 < 32; i4 += 4) {
    int d0 = w * 64 + h * 32 + i4;  // 16B-aligned
    float4 v4 = *(const float4*)(erow + d0);
#pragma unroll
    for (int m = 0; m < 4; m++) {
      float v = (m == 0) ? v4.x : (m == 1) ? v4.y : (m == 2) ? v4.z : v4.w;
      float zv = zb[(size_t)(d0 + m) * SPATIAL + t];
      float df = __fsub_rn(v, zv);
      sumsq = fmaf(df, df, sumsq);
      op[(size_t)(d0 + m) * SPATIAL + t] = v;  // coalesced 128B/instr
    }
  }
#pragma unroll
  for (int o = 32; o > 0; o >>= 1) sumsq += __shfl_down(sumsq, o, 64);
  if (lane == 0) red[w] = sumsq;
  __syncthreads();
  if (tid == 0) {
    atomicAdd(ws + WS_LOSS, red[0] + red[1] + red[2] + red[3]);
    __threadfence();  // loss add globally visible before counter bump
    unsigned tcnt = atomicAdd((unsigned*)ws + WS_CNT, 1u);
    if (tcnt == NBLK - 1) {  // last block publishes loss
      float total = atomicAdd(ws + WS_LOSS, 0.f);  // device-scope read
      out[O_LOSS] = 1.25f * total / 8388608.f;
    }
  }
}

extern "C" void kernel_launch(void* const* d_in, const int* in_sizes, int n_in,
                              void* d_out, int out_size, void* d_ws, size_t ws_size,
                              hipStream_t stream) {
  const float* z = (const float*)d_in[0];
  const float* e = (const float*)d_in[1];
  float* ws = (float*)d_ws;
  float* out = (float*)d_out;

  prep_kernel<<<K_CODES, 256, 0, stream>>>(e, ws);
  main_kernel<<<NBLK, 256, 0, stream>>>(z, e, ws, out);
}